// Round 2
// baseline (597.645 us; speedup 1.0000x reference)
//
#include <hip/hip_runtime.h>

#define T_STEPS 256
#define IMG 512
#define HW (IMG * IMG)

// out[t] = 0.8*out[t-1] + conv(x)[t-1]; out[0]=0 — conv and LI scan commute.
// No LDS, no barriers: each 64-thread block is one wave owning one output row
// segment of 128 cols (2 cols/lane). Register ring-3 pipeline over t keeps
// global loads in flight (no __syncthreads -> no vmcnt(0) drain).
__launch_bounds__(64)
__global__ void conv_li_kernel(const float* __restrict__ x,
                               const float* __restrict__ kern,
                               float* __restrict__ out) {
    const int lane = threadIdx.x;
    const int bid = blockIdx.x;
    // 2048 blocks, 8 XCDs, 256 contiguous per XCD (bijective: 2048 % 8 == 0).
    const int swz = (bid & 7) * 256 + (bid >> 3);
    const int r = swz >> 2;          // output row 0..511
    const int q = swz & 3;           // 128-col quarter
    const int g0 = q * 128 + lane * 2;  // first of this lane's 2 output cols

    // 5x5 kernel weights -> wave-uniform SGPRs.
    float kw[25];
#pragma unroll
    for (int i = 0; i < 25; ++i)
        kw[i] = __int_as_float(__builtin_amdgcn_readfirstlane(__float_as_int(kern[i])));

    const bool okL = (g0 >= 2);      // window cols g0-2,g0-1 valid
    const bool okR = (g0 <= 508);    // window cols g0+2,g0+3 valid

    bool rowok[5];
    const float* rowp[5];            // &x[row*IMG + g0] (frame 0), safe row if OOB
#pragma unroll
    for (int dy = 0; dy < 5; ++dy) {
        int ry = r - 2 + dy;
        rowok[dy] = (ry >= 0) && (ry < IMG);
        rowp[dy] = x + (size_t)(rowok[dy] ? ry : 0) * IMG + g0;
    }
    // Safe per-lane byte displacements for the left/right float2 of the window.
    const int dL = okL ? -2 : 0;
    const int dR = okR ? 2 : 0;

    float2 b0[5][3], b1[5][3], b2[5][3];
    const float2 z = make_float2(0.f, 0.f);

    auto LOAD = [&](float2(*buf)[3], int t) {
        const size_t toff = (size_t)t * HW;
#pragma unroll
        for (int dy = 0; dy < 5; ++dy) {
            if (rowok[dy]) {
                const float* rp = rowp[dy] + toff;
                float2 vL = *(const float2*)(rp + dL);
                float2 vM = *(const float2*)(rp);
                float2 vR = *(const float2*)(rp + dR);
                buf[dy][0] = okL ? vL : z;
                buf[dy][1] = vM;
                buf[dy][2] = okR ? vR : z;
            } else {
                buf[dy][0] = z; buf[dy][1] = z; buf[dy][2] = z;
            }
        }
    };

    float2 st = make_float2(0.f, 0.f);
    float* const outbase = out + (size_t)r * IMG + g0;

    auto STEP = [&](float2(*buf)[3], int t) {
        float ax = 0.f, ay = 0.f;
#pragma unroll
        for (int dy = 0; dy < 5; ++dy) {
            const float w0 = buf[dy][0].x, w1 = buf[dy][0].y;
            const float w2 = buf[dy][1].x, w3 = buf[dy][1].y;
            const float w4 = buf[dy][2].x, w5 = buf[dy][2].y;
            ax = fmaf(kw[dy * 5 + 0], w0, ax);
            ax = fmaf(kw[dy * 5 + 1], w1, ax);
            ax = fmaf(kw[dy * 5 + 2], w2, ax);
            ax = fmaf(kw[dy * 5 + 3], w3, ax);
            ax = fmaf(kw[dy * 5 + 4], w4, ax);
            ay = fmaf(kw[dy * 5 + 0], w1, ay);
            ay = fmaf(kw[dy * 5 + 1], w2, ay);
            ay = fmaf(kw[dy * 5 + 2], w3, ay);
            ay = fmaf(kw[dy * 5 + 3], w4, ay);
            ay = fmaf(kw[dy * 5 + 4], w5, ay);
        }
        *(float2*)(outbase + (size_t)t * HW) = st;   // out[t] = S_{t-1}
        st.x = st.x - 0.2f * st.x + ax;              // S_t = 0.8*S_{t-1} + y[t]
        st.y = st.y - 0.2f * st.y + ay;
    };

    // Ring-3 register pipeline, prefetch distance 2.
    LOAD(b0, 0);
    LOAD(b1, 1);
    int t = 0;
    for (int it = 0; it < 84; ++it) {   // covers t = 0..251
        LOAD(b2, t + 2); STEP(b0, t);
        LOAD(b0, t + 3); STEP(b1, t + 1);
        LOAD(b1, t + 4); STEP(b2, t + 2);
        t += 3;
    }
    // t == 252 here; b0 holds frame 252, b1 holds 253.
    LOAD(b2, 254); STEP(b0, 252);
    LOAD(b0, 255); STEP(b1, 253);
    STEP(b2, 254);
    STEP(b0, 255);
}

extern "C" void kernel_launch(void* const* d_in, const int* in_sizes, int n_in,
                              void* d_out, int out_size, void* d_ws, size_t ws_size,
                              hipStream_t stream) {
    const float* x = (const float*)d_in[0];      // [256,1,512,512] f32
    const float* kern = (const float*)d_in[1];   // [5,5] f32
    float* out = (float*)d_out;                  // [256,1,512,512] f32

    conv_li_kernel<<<dim3(2048), dim3(64), 0, stream>>>(x, kern, out);
}

// Round 3
// 248.385 us; speedup vs baseline: 2.4061x; 2.4061x over previous
//
#include <hip/hip_runtime.h>

#define T_STEPS 256
#define IMG 512
#define HW (IMG * IMG)
#define TW 32
#define TH 8
#define HTW (TW + 4)              // 36 floats per halo row
#define HTH (TH + 4)              // 12 halo rows
#define HALO_N (HTH * HTW)        // 432 floats
#define HALO_F2 (HALO_N / 2)      // 216 float2
#define NTHREADS 128
#define NSTG 2                    // ceil(216/128)

// out[t] = 0.8*out[t-1] + conv(x)[t-1]; out[0]=0 — conv and LI scan commute.
// 1024 blocks (4/CU, 8 waves/CU) so barrier drains overlap across blocks.
// LDS double-buffered halo tile, b64 reads (thread = 2 cols x 1 row).
__launch_bounds__(NTHREADS, 2)
__global__ void conv_li_kernel(const float* __restrict__ x,
                               const float* __restrict__ kern,
                               float* __restrict__ out) {
    __shared__ float lds[2][HALO_N];
    const int tid = threadIdx.x;
    const int bid = blockIdx.x;
    // 1024 blocks over 8 XCDs, bijective (1024%8==0): XCD k owns 128
    // contiguous vbids = 8 contiguous tile-row bands -> vertical halo
    // sharing stays in one XCD's L2.
    const int vbid = (bid & 7) * 128 + (bid >> 3);
    const int bx = vbid & 15;     // 16 tiles across
    const int by = vbid >> 4;     // 64 tile rows

    // 5x5 kernel -> wave-uniform SGPRs.
    float kw[25];
#pragma unroll
    for (int i = 0; i < 25; ++i)
        kw[i] = __int_as_float(__builtin_amdgcn_readfirstlane(__float_as_int(kern[i])));

    // Staging geometry (t-invariant), float2 granularity. gx is always even
    // so float2 loads are 8B-aligned and never straddle the image edge.
    size_t goff[NSTG];
    bool gok[NSTG];
    int laddr[NSTG];
    bool lok[NSTG];
#pragma unroll
    for (int q = 0; q < NSTG; ++q) {
        int e2 = tid + q * NTHREADS;
        lok[q] = (e2 < HALO_F2);
        int row = e2 / 18;        // 18 float2 per halo row
        int cp = e2 - row * 18;
        int gy = by * TH + row - 2;
        int gx = bx * TW + cp * 2 - 2;
        bool ok = lok[q] && gy >= 0 && gy < IMG && gx >= 0 && gx <= (IMG - 2);
        gok[q] = ok;
        goff[q] = ok ? ((size_t)gy * IMG + gx) : 0;
        laddr[q] = row * HTW + cp * 2;
    }

    const int p = tid & 15;       // col-pair 0..15
    const int rr = tid >> 4;      // out row within tile 0..7

    float2 rA[NSTG], rB[NSTG];
    const float2 z = make_float2(0.f, 0.f);

    auto LOAD = [&](float2* rv, int t) {
#pragma unroll
        for (int q = 0; q < NSTG; ++q)
            rv[q] = gok[q] ? *(const float2*)(x + goff[q] + (size_t)t * HW) : z;
    };
    auto WRITE_LDS = [&](int buf, const float2* rv) {
#pragma unroll
        for (int q = 0; q < NSTG; ++q)
            if (lok[q]) *(float2*)(&lds[buf][laddr[q]]) = rv[q];
    };

    float2 st = z;
    float* const outbase = out + (size_t)(by * TH + rr) * IMG + bx * TW + p * 2;

    auto STEP = [&](int buf, int t) {
        float ax = 0.f, ay = 0.f;
        const float* base = &lds[buf][rr * HTW + p * 2];
#pragma unroll
        for (int dy = 0; dy < 5; ++dy) {
            const float* L = base + dy * HTW;
            float2 a = *(const float2*)(L);       // halo cols 2p, 2p+1
            float2 b = *(const float2*)(L + 2);   // 2p+2, 2p+3
            float2 c = *(const float2*)(L + 4);   // 2p+4, 2p+5
            ax = fmaf(kw[dy * 5 + 0], a.x, ax);
            ax = fmaf(kw[dy * 5 + 1], a.y, ax);
            ax = fmaf(kw[dy * 5 + 2], b.x, ax);
            ax = fmaf(kw[dy * 5 + 3], b.y, ax);
            ax = fmaf(kw[dy * 5 + 4], c.x, ax);
            ay = fmaf(kw[dy * 5 + 0], a.y, ay);
            ay = fmaf(kw[dy * 5 + 1], b.x, ay);
            ay = fmaf(kw[dy * 5 + 2], b.y, ay);
            ay = fmaf(kw[dy * 5 + 3], c.x, ay);
            ay = fmaf(kw[dy * 5 + 4], c.y, ay);
        }
        *(float2*)(outbase + (size_t)t * HW) = st;  // out[t] = S_{t-1}
        st.x = st.x - 0.2f * st.x + ax;             // S_t = 0.8*S_{t-1} + y[t]
        st.y = st.y - 0.2f * st.y + ay;
    };

    // Prologue: rA<-frame0, rB<-frame1, stage frame0 into lds[0].
    LOAD(rA, 0);
    LOAD(rB, 1);
    WRITE_LDS(0, rA);
    __syncthreads();

    int t = 0;
    while (true) {
        // even t: compute from lds[0]; rA free -> prefetch t+2; rB -> lds[1]
        if (t + 2 < T_STEPS) LOAD(rA, t + 2);
        STEP(0, t);
        if (t + 1 < T_STEPS) WRITE_LDS(1, rB);
        __syncthreads();
        ++t;
        if (t >= T_STEPS) break;

        // odd t: compute from lds[1]; rB free -> prefetch t+2; rA -> lds[0]
        if (t + 2 < T_STEPS) LOAD(rB, t + 2);
        STEP(1, t);
        if (t + 1 < T_STEPS) WRITE_LDS(0, rA);
        __syncthreads();
        ++t;
        if (t >= T_STEPS) break;
    }
}

extern "C" void kernel_launch(void* const* d_in, const int* in_sizes, int n_in,
                              void* d_out, int out_size, void* d_ws, size_t ws_size,
                              hipStream_t stream) {
    const float* x = (const float*)d_in[0];      // [256,1,512,512] f32
    const float* kern = (const float*)d_in[1];   // [5,5] f32
    float* out = (float*)d_out;                  // [256,1,512,512] f32

    conv_li_kernel<<<dim3(1024), dim3(NTHREADS), 0, stream>>>(x, kern, out);
}

// Round 4
// 159.640 us; speedup vs baseline: 3.7437x; 1.5559x over previous
//
#include <hip/hip_runtime.h>

#define T_STEPS 256
#define IMG 512
#define HW (IMG * IMG)
#define TW 32
#define TH 8
#define HTW 36                 // halo row floats (32 + 4)
#define HTH 12                 // halo rows (8 + 4)
#define HALO_N (HTH * HTW)     // 432 floats
#define NCHUNK (HALO_N / 4)    // 108 float4 chunks, exactly 9 per halo row

struct C4 { float2 lo, hi; };  // one 16B staging chunk (two float2 halves)

// out[t] = 0.8*out[t-1] + conv(x)[t-1]; out[0]=0 — conv and LI scan commute.
// Single-wave blocks: DS ops are in-order within a wave -> NO barriers, no
// vmcnt(0) drains. Ring-2 LDS + ring-3 reg slots: load issued at step t is
// consumed (ds_write) at t+3 -> ~3 steps of HBM-latency slack, always in
// flight. All LDS reads are conflict-free ds_read_b128.
__launch_bounds__(64)
__global__ void conv_li_kernel(const float* __restrict__ x,
                               const float* __restrict__ kern,
                               float* __restrict__ out) {
    __shared__ __align__(16) float lds[2][HALO_N];
    const int tid = threadIdx.x;
    const int bid = blockIdx.x;
    // 1024 blocks over 8 XCDs, bijective (1024 % 8 == 0): each XCD owns 8
    // contiguous tile-row bands -> vertical halo sharing stays in its L2.
    const int vbid = (bid & 7) * 128 + (bid >> 3);
    const int bx = vbid & 15;      // 16 tiles across
    const int by = vbid >> 4;      // 64 tile rows

    // 5x5 kernel -> wave-uniform (SGPR) weights.
    float kw[25];
#pragma unroll
    for (int i = 0; i < 25; ++i)
        kw[i] = __int_as_float(__builtin_amdgcn_readfirstlane(__float_as_int(kern[i])));

    // Staging geometry (t-invariant). Thread stages chunk tid and, if
    // tid < NCHUNK-64, chunk tid+64. Each chunk = 2 float2 halves with
    // independent validity (handles partial edge chunks).
    int goff[2][2];
    bool gok[2][2];
#pragma unroll
    for (int cc = 0; cc < 2; ++cc) {
        int c = tid + cc * 64;
        bool cok = (c < NCHUNK);
        int row = c / 9;           // halo row
        int cq = c - row * 9;      // chunk within row
        int gy = by * TH + row - 2;
#pragma unroll
        for (int h = 0; h < 2; ++h) {
            int gx = bx * TW + cq * 4 + h * 2 - 2;   // always even
            bool ok = cok && gy >= 0 && gy < IMG && gx >= 0 && gx <= (IMG - 2);
            gok[cc][h] = ok;
            goff[cc][h] = ok ? (gy * IMG + gx) : 0;
        }
    }

    const int q = tid & 7;         // col-quad (4 cols each)
    const int rr = tid >> 3;       // out row within tile
    const size_t obase = (size_t)(by * TH + rr) * IMG + bx * TW + q * 4;

    const float2 z2 = make_float2(0.f, 0.f);
    C4 sA0, sA1, sB0, sB1, sC0, sC1;   // 3 ring slots x 2 chunks

    auto LOADS = [&](C4& a, C4& b, int tf) {
        const float* xb = x + (size_t)tf * HW;
        a.lo = gok[0][0] ? *(const float2*)(xb + goff[0][0]) : z2;
        a.hi = gok[0][1] ? *(const float2*)(xb + goff[0][1]) : z2;
        b.lo = gok[1][0] ? *(const float2*)(xb + goff[1][0]) : z2;
        b.hi = gok[1][1] ? *(const float2*)(xb + goff[1][1]) : z2;
    };
    auto DSW = [&](int LB, const C4& a, const C4& b) {
        *(C4*)&lds[LB][tid * 4] = a;
        if (tid < NCHUNK - 64) *(C4*)&lds[LB][(tid + 64) * 4] = b;
    };

    float4 st = make_float4(0.f, 0.f, 0.f, 0.f);

    auto STEP = [&](int LB, int t) {
        float4 acc = make_float4(0.f, 0.f, 0.f, 0.f);
        const float* Bp = &lds[LB][rr * HTW + q * 4];
#pragma unroll
        for (int dy = 0; dy < 5; ++dy) {
            float4 w0 = *(const float4*)(Bp + dy * HTW);       // halo cols 4q..4q+3
            float4 w1 = *(const float4*)(Bp + dy * HTW + 4);   // 4q+4..4q+7
            const float a0 = w0.x, a1 = w0.y, a2 = w0.z, a3 = w0.w;
            const float a4 = w1.x, a5 = w1.y, a6 = w1.z, a7 = w1.w;
            const float k0 = kw[dy * 5 + 0], k1 = kw[dy * 5 + 1], k2 = kw[dy * 5 + 2];
            const float k3 = kw[dy * 5 + 3], k4 = kw[dy * 5 + 4];
            acc.x = fmaf(k0, a0, acc.x); acc.x = fmaf(k1, a1, acc.x);
            acc.x = fmaf(k2, a2, acc.x); acc.x = fmaf(k3, a3, acc.x);
            acc.x = fmaf(k4, a4, acc.x);
            acc.y = fmaf(k0, a1, acc.y); acc.y = fmaf(k1, a2, acc.y);
            acc.y = fmaf(k2, a3, acc.y); acc.y = fmaf(k3, a4, acc.y);
            acc.y = fmaf(k4, a5, acc.y);
            acc.z = fmaf(k0, a2, acc.z); acc.z = fmaf(k1, a3, acc.z);
            acc.z = fmaf(k2, a4, acc.z); acc.z = fmaf(k3, a5, acc.z);
            acc.z = fmaf(k4, a6, acc.z);
            acc.w = fmaf(k0, a3, acc.w); acc.w = fmaf(k1, a4, acc.w);
            acc.w = fmaf(k2, a5, acc.w); acc.w = fmaf(k3, a6, acc.w);
            acc.w = fmaf(k4, a7, acc.w);
        }
        *(float4*)(out + (size_t)t * HW + obase) = st;   // out[t] = S_{t-1}
        st.x = st.x - 0.2f * st.x + acc.x;               // S_t = 0.8*S_{t-1} + y[t]
        st.y = st.y - 0.2f * st.y + acc.y;
        st.z = st.z - 0.2f * st.z + acc.z;
        st.w = st.w - 0.2f * st.w + acc.w;
    };

    // Prologue: frames 0..4 staged/loaded; slot = frame % 3 (A=0,B=1,C=2).
    LOADS(sA0, sA1, 0);
    LOADS(sB0, sB1, 1);
    LOADS(sC0, sC1, 2);
    DSW(0, sA0, sA1);          // lds[0] <- frame 0
    LOADS(sA0, sA1, 3);
    DSW(1, sB0, sB1);          // lds[1] <- frame 1
    LOADS(sB0, sB1, 4);

    // Per step t: compute from lds[t%2] (frame t), then overwrite it with
    // frame t+2 from slot (t+2)%3, then reload that slot with frame t+5.
#define ITER(T, LB, S0, S1)                                  \
    do {                                                     \
        STEP(LB, (T));                                       \
        DSW(LB, S0, S1);                                     \
        int tf = (T) + 5; if (tf > 255) tf = 255;            \
        LOADS(S0, S1, tf);                                   \
        __builtin_amdgcn_sched_barrier(0);                   \
    } while (0)

#pragma clang loop unroll(disable)
    for (int tb = 0; tb < 252; tb += 6) {
        ITER(tb + 0, 0, sC0, sC1);
        ITER(tb + 1, 1, sA0, sA1);
        ITER(tb + 2, 0, sB0, sB1);
        ITER(tb + 3, 1, sC0, sC1);
        ITER(tb + 4, 0, sA0, sA1);
        ITER(tb + 5, 1, sB0, sB1);
    }
    ITER(252, 0, sC0, sC1);
    ITER(253, 1, sA0, sA1);
    ITER(254, 0, sB0, sB1);
    ITER(255, 1, sC0, sC1);
#undef ITER
}

extern "C" void kernel_launch(void* const* d_in, const int* in_sizes, int n_in,
                              void* d_out, int out_size, void* d_ws, size_t ws_size,
                              hipStream_t stream) {
    const float* x = (const float*)d_in[0];      // [256,1,512,512] f32
    const float* kern = (const float*)d_in[1];   // [5,5] f32
    float* out = (float*)d_out;                  // [256,1,512,512] f32

    conv_li_kernel<<<dim3(1024), dim3(64), 0, stream>>>(x, kern, out);
}